// Round 8
// baseline (334.286 us; speedup 1.0000x reference)
//
#include <hip/hip_runtime.h>
#include <math.h>

#define D_MODEL 1024
#define NUM_HEADS 16
#define DK 64
#define BATCH 2
#define SEQ 2048

using f32x4  = __attribute__((ext_vector_type(4))) float;
using bf16x8 = __attribute__((ext_vector_type(8))) short;
using us8    = __attribute__((ext_vector_type(8))) unsigned short;

__device__ __forceinline__ unsigned short f2b(float x) {  // fp32 -> bf16 RNE
    unsigned u = __float_as_uint(x);
    return (unsigned short)((u + 0x7FFF + ((u >> 16) & 1)) >> 16);
}
__device__ __forceinline__ float b2f(unsigned short h) {
    return __uint_as_float(((unsigned)h) << 16);
}
__device__ __forceinline__ void gl_lds16(const unsigned short* g, unsigned short* l) {
    __builtin_amdgcn_global_load_lds(
        (const __attribute__((address_space(1))) void*)g,
        (__attribute__((address_space(3))) void*)l, 16, 0, 0);
}

// ---------------------------------------------------------------------------
// Per-batch prefix scan of mask: pos[b][s] = #valid keys before s, nc[b]=count
// ---------------------------------------------------------------------------
__global__ __launch_bounds__(256) void mask_scan_kernel(
    const int* __restrict__ mask, int* __restrict__ pos, int* __restrict__ nc)
{
    const int b = blockIdx.x;
    const int tid = threadIdx.x;
    __shared__ int sums[256];
    int v[8]; int cnt = 0;
    const int base = b * SEQ + tid * 8;
    #pragma unroll
    for (int e = 0; e < 8; ++e) { v[e] = (mask[base + e] != 0) ? 1 : 0; cnt += v[e]; }
    sums[tid] = cnt;
    __syncthreads();
    for (int off = 1; off < 256; off <<= 1) {
        int t = (tid >= off) ? sums[tid - off] : 0;
        __syncthreads();
        sums[tid] += t;
        __syncthreads();
    }
    int run = sums[tid] - cnt;           // exclusive prefix
    #pragma unroll
    for (int e = 0; e < 8; ++e) { pos[base + e] = run; run += v[e]; }
    if (tid == 255) nc[b] = sums[255];
}

// ---------------------------------------------------------------------------
// fp32 [rows][1024] -> bf16 [rows][2048] = [hi | lo] along K, row-XOR swizzle
// baked in (stored 16B block ss holds logical block ss ^ (row&7), per 64-col
// group). Up to 4 (src,dst) pairs selected by blockIdx.y. grid.x = rows.
// ---------------------------------------------------------------------------
__global__ __launch_bounds__(256) void conv_hilo_kernel(
    const float* s0, const float* s1, const float* s2, const float* s3,
    unsigned short* d0, unsigned short* d1, unsigned short* d2, unsigned short* d3,
    int rows)
{
    const int y = blockIdx.y;
    const float* src = (y == 0) ? s0 : (y == 1) ? s1 : (y == 2) ? s2 : s3;
    unsigned short* dst = (y == 0) ? d0 : (y == 1) ? d1 : (y == 2) ? d2 : d3;
    const int id = blockIdx.x * 256 + threadIdx.x;
    if (id >= rows * 256) return;
    const int row = id >> 8;
    const int s   = id & 255;                // stored 16B-block index in [0,256)
    const int g   = s >> 3, ss = s & 7;
    const int lb  = ss ^ (row & 7);          // logical block within 64-col group
    const int srcg = g & 15;                 // source 64-col group
    const bool lo = (g >> 4) != 0;           // second K-half = residual

    const float* p = src + (size_t)row * 1024 + srcg * 64 + lb * 8;
    const float4 a = *(const float4*)p;
    const float4 bq = *(const float4*)(p + 4);
    const float xs[8] = {a.x, a.y, a.z, a.w, bq.x, bq.y, bq.z, bq.w};
    us8 o;
    #pragma unroll
    for (int e = 0; e < 8; ++e) {
        float x = xs[e];
        if (lo) { unsigned short h = f2b(x); x = x - b2f(h); }
        o[e] = f2b(x);
    }
    *(us8*)&dst[(size_t)row * 2048 + s * 8] = o;
}

// ---------------------------------------------------------------------------
// Shared GEMM body via macro-free structure: 128x64 tile, BK=64, 4 waves x
// (64x32), double-buffered LDS, global_load_lds x16B. Virtual K sweep of 48
// tiles over [hi|lo] operands gives 3-term hi/lo product:
//   vkt  0-15: Ahi*Whi   16-31: Alo*Whi   32-47: Ahi*Wlo
// ---------------------------------------------------------------------------
#define GEMM_BODY(A2, W2)                                                      \
    constexpr int KS = 2048;                                                   \
    __shared__ bf16x8 Asl[2][1024];                                            \
    __shared__ bf16x8 Bsl[2][512];                                             \
    const int tid = threadIdx.x;                                               \
    const int wv = tid >> 6, ln = tid & 63;                                    \
    const int wm = wv >> 1, wn = wv & 1;                                       \
    const int bm = blockIdx.x * 128, bn = blockIdx.y * 64;                     \
    const int x = ln & 15, y = ln >> 4;                                        \
    f32x4 acc[4][2] = {};                                                      \
    const unsigned short* Ab = (A2) + (size_t)bm * KS;                         \
    const unsigned short* Bb = (W2) + (size_t)bn * KS;                         \
    const int srow = ln >> 3;                                                  \
    const int scol = (ln & 7) * 8;                                             \
    auto stage = [&](int bufi, int vkt) {                                      \
        const int a_kt = (vkt < 32) ? vkt : vkt - 32;                          \
        const int w_kt = (vkt < 32) ? (vkt & 15) : vkt - 16;                   \
        _Pragma("unroll")                                                      \
        for (int c = 0; c < 4; ++c) {                                          \
            const int rowb = wv * 32 + c * 8;                                  \
            gl_lds16(Ab + (size_t)(rowb + srow) * KS + a_kt * 64 + scol,       \
                     (unsigned short*)&Asl[bufi][rowb << 3]);                  \
        }                                                                      \
        _Pragma("unroll")                                                      \
        for (int c = 0; c < 2; ++c) {                                          \
            const int rowb = wv * 16 + c * 8;                                  \
            gl_lds16(Bb + (size_t)(rowb + srow) * KS + w_kt * 64 + scol,       \
                     (unsigned short*)&Bsl[bufi][rowb << 3]);                  \
        }                                                                      \
    };                                                                         \
    stage(0, 0);                                                               \
    asm volatile("s_waitcnt vmcnt(0)" ::: "memory");                           \
    __syncthreads();                                                           \
    int buf = 0;                                                               \
    for (int kt = 0; kt < 48; ++kt) {                                          \
        if (kt < 47) stage(buf ^ 1, kt + 1);                                   \
        _Pragma("unroll")                                                      \
        for (int half = 0; half < 2; ++half) {                                 \
            bf16x8 af[4], bfr[2];                                              \
            _Pragma("unroll")                                                  \
            for (int mf = 0; mf < 4; ++mf) {                                   \
                const int r = wm * 64 + mf * 16 + x;                           \
                af[mf] = Asl[buf][(r << 3) | ((half * 4 + y) ^ (r & 7))];      \
            }                                                                  \
            _Pragma("unroll")                                                  \
            for (int nf = 0; nf < 2; ++nf) {                                   \
                const int r = wn * 32 + nf * 16 + x;                           \
                bfr[nf] = Bsl[buf][(r << 3) | ((half * 4 + y) ^ (r & 7))];     \
            }                                                                  \
            _Pragma("unroll")                                                  \
            for (int mf = 0; mf < 4; ++mf)                                     \
                _Pragma("unroll")                                              \
                for (int nf = 0; nf < 2; ++nf)                                 \
                    acc[mf][nf] = __builtin_amdgcn_mfma_f32_16x16x32_bf16(     \
                        af[mf], bfr[nf], acc[mf][nf], 0, 0, 0);                \
        }                                                                      \
        asm volatile("s_waitcnt vmcnt(0)" ::: "memory");                       \
        __syncthreads();                                                       \
        buf ^= 1;                                                              \
    }

// MODE 0: fp32 [M][1024];  MODE 1: fp32 split [b][h][s][dk]
template <int MODE>
__global__ __launch_bounds__(256) void mfma_gemm_kernel(
    const unsigned short* __restrict__ A2, const unsigned short* __restrict__ W2,
    const float* __restrict__ bias, float* __restrict__ Cf)
{
    GEMM_BODY(A2, W2)
    #pragma unroll
    for (int nf = 0; nf < 2; ++nf) {
        const int n = bn + wn * 32 + nf * 16 + x;
        const float bv = bias[n];
        #pragma unroll
        for (int mf = 0; mf < 4; ++mf) {
            const int mbase = bm + wm * 64 + mf * 16 + y * 4;
            #pragma unroll
            for (int r = 0; r < 4; ++r) {
                const int m = mbase + r;
                const float v = acc[mf][nf][r] + bv;
                if (MODE == 0) {
                    Cf[(size_t)m * D_MODEL + n] = v;
                } else {
                    const int b = m >> 11, s = m & (SEQ - 1);
                    const int hh = n >> 6, dd = n & 63;
                    Cf[((size_t)((b * NUM_HEADS + hh) * SEQ + s)) * DK + dd] = v;
                }
            }
        }
    }
}

// K and V projection GEMMs merged: blockIdx.z = 0 -> K2, 1 -> VT2 (compacted)
__global__ __launch_bounds__(256) void mfma_gemm_kv_kernel(
    const unsigned short* __restrict__ actK, const unsigned short* __restrict__ actV,
    const unsigned short* __restrict__ w2k, const unsigned short* __restrict__ w2v,
    const float* __restrict__ bk, const float* __restrict__ bv,
    unsigned short* __restrict__ k2, unsigned short* __restrict__ vt2,
    const int* __restrict__ mask, const int* __restrict__ pos)
{
    const int z = blockIdx.z;
    const unsigned short* A2 = z ? actV : actK;
    const unsigned short* W2 = z ? w2v : w2k;
    const float* bias = z ? bv : bk;
    GEMM_BODY(A2, W2)
    #pragma unroll
    for (int nf = 0; nf < 2; ++nf) {
        const int n = bn + wn * 32 + nf * 16 + x;
        const float bvv = bias[n];
        #pragma unroll
        for (int mf = 0; mf < 4; ++mf) {
            const int mbase = bm + wm * 64 + mf * 16 + y * 4;
            #pragma unroll
            for (int r = 0; r < 4; ++r) {
                const int m = mbase + r;
                const float v = acc[mf][nf][r] + bvv;
                const int b = m >> 11, s = m & (SEQ - 1);
                const int hh = n >> 6, dd = n & 63;
                if (!mask[b * SEQ + s]) continue;
                const int p = pos[b * SEQ + s];
                if (z == 0) {
                    // K2: [bh][kpos][128] = hi(64,swz) | lo(64,swz)
                    const unsigned short hi = f2b(v);
                    const unsigned short lo = f2b(v - b2f(hi));
                    const int blk = (dd >> 3) ^ (p & 7), i = dd & 7;
                    unsigned short* kp = k2 +
                        ((size_t)((b * NUM_HEADS + hh) * SEQ + p)) * 128;
                    kp[blk * 8 + i] = hi;
                    kp[64 + blk * 8 + i] = lo;
                } else {
                    // VT2: [bh][d][2048], key-block swizzle by d&7 per 64-tile
                    const int tile = p >> 6, w = p & 63;
                    const int blk = (w >> 3) ^ (dd & 7), i = w & 7;
                    vt2[((size_t)((b * NUM_HEADS + hh) * DK + dd)) * SEQ +
                        tile * 64 + blk * 8 + i] = f2b(v);
                }
            }
        }
    }
}

// ---------------------------------------------------------------------------
// MFMA flash attention over COMPACTED keys, double-buffered K/V staging:
// issue next tile's global_load_lds before computing the current tile; one
// vmcnt(0)+barrier per iteration. Block = 4 waves, one (b,h) x 64-q-row tile.
// ---------------------------------------------------------------------------
__global__ __launch_bounds__(256, 2) void attn_mfma_kernel(
    const float* __restrict__ Q, const unsigned short* __restrict__ K2,
    const unsigned short* __restrict__ VT2, const int* __restrict__ ncArr,
    float* __restrict__ CTX)
{
    __shared__ __align__(16) unsigned short SM[28672];   // 56 KB
    // per buffer (12288 shorts): Khi [64k][64d] | Klo | VTs [64d][64k]
    const int tid = threadIdx.x;
    const int wave = tid >> 6, lane = tid & 63;
    const int lo4 = lane & 15, hi4 = lane >> 4;
    unsigned short* Pw = SM + 24576 + wave * 1024;  // [16 q][64 key] bf16

    const int orig = blockIdx.x;
    const int swz = (orig & 7) * 128 + (orig >> 3);  // 1024%8==0: bijective
    const int bh = swz >> 5, qblk = swz & 31;
    const int b = bh >> 4, h = bh & 15;

    const float* Qb = Q + (size_t)bh * SEQ * DK;
    const unsigned short* Kb = K2 + (size_t)bh * SEQ * 128;
    const unsigned short* Vb = VT2 + (size_t)bh * DK * SEQ;

    const int ncb = ncArr[b];
    const int nt = (ncb + 63) >> 6;

    auto stage_kv = [&](int bufi, int k0) {
        #pragma unroll
        for (int j = 0; j < 6; ++j) {
            const int g = j * 256 + wave * 64;   // wave-uniform dest base
            const int gi = g + lane;
            const unsigned short* src;
            if (gi < 512) {
                src = Kb + (size_t)(k0 + (gi >> 3)) * 128 + (gi & 7) * 8;
            } else if (gi < 1024) {
                const int g2 = gi - 512;
                src = Kb + (size_t)(k0 + (g2 >> 3)) * 128 + 64 + (g2 & 7) * 8;
            } else {
                const int g3 = gi - 1024;
                src = Vb + (size_t)(g3 >> 3) * SEQ + k0 + (g3 & 7) * 8;
            }
            gl_lds16(src, SM + (size_t)bufi * 12288 + (size_t)g * 8);
        }
    };

    // Q fragments (hi/lo of q/8): row = q = lane&15, k = (lane>>4)*8+i
    const int qr = qblk * 64 + wave * 16 + lo4;
    bf16x8 qhi[2], qlo[2];
    #pragma unroll
    for (int c = 0; c < 2; ++c) {
        const float* qp = &Qb[(size_t)qr * DK + c * 32 + hi4 * 8];
        const float4 x0 = *(const float4*)qp;
        const float4 x1 = *(const float4*)(qp + 4);
        const float xs[8] = {x0.x, x0.y, x0.z, x0.w, x1.x, x1.y, x1.z, x1.w};
        #pragma unroll
        for (int i = 0; i < 8; ++i) {
            const float sx = xs[i] * 0.125f;
            const unsigned short hh = f2b(sx);
            qhi[c][i] = (short)hh;
            qlo[c][i] = (short)f2b(sx - b2f(hh));
        }
    }

    f32x4 ctx[4] = {};   // ctx^T frags: row d = dt*16+hi4*4+r, col q = lo4
    float m = -INFINITY, l = 0.f;

    stage_kv(0, 0);
    asm volatile("s_waitcnt vmcnt(0)" ::: "memory");
    __syncthreads();

    int buf = 0;
    for (int t = 0; t < nt; ++t) {
        if (t + 1 < nt) stage_kv(buf ^ 1, (t + 1) * 64);   // overlap compute

        const unsigned short* Khi = SM + buf * 12288;
        const unsigned short* Klo = Khi + 4096;
        const unsigned short* VTs = Khi + 8192;
        const int k0 = t * 64;

        // S^T = K . Q^T : rows = key, cols = q (hi/lo 3-term, fp32-accurate)
        f32x4 sc[4];
        #pragma unroll
        for (int kt = 0; kt < 4; ++kt) {
            f32x4 s = {0.f, 0.f, 0.f, 0.f};
            const int row = kt * 16 + lo4;
            const int rx = row & 7;
            #pragma unroll
            for (int c = 0; c < 2; ++c) {
                const int blk = ((c * 4 + hi4) ^ rx) * 8;
                const bf16x8 kh = *(bf16x8*)&Khi[row * 64 + blk];
                const bf16x8 kl = *(bf16x8*)&Klo[row * 64 + blk];
                s = __builtin_amdgcn_mfma_f32_16x16x32_bf16(kh, qhi[c], s, 0, 0, 0);
                s = __builtin_amdgcn_mfma_f32_16x16x32_bf16(kl, qhi[c], s, 0, 0, 0);
                s = __builtin_amdgcn_mfma_f32_16x16x32_bf16(kh, qlo[c], s, 0, 0, 0);
            }
            sc[kt] = s;
        }

        // row-max; tail tile masks invalid keys (kidx >= ncb) to -1e30
        float cmax = -1e30f;
        if (k0 + 64 <= ncb) {
            #pragma unroll
            for (int kt = 0; kt < 4; ++kt)
                #pragma unroll
                for (int r = 0; r < 4; ++r) cmax = fmaxf(cmax, sc[kt][r]);
        } else {
            #pragma unroll
            for (int kt = 0; kt < 4; ++kt)
                #pragma unroll
                for (int r = 0; r < 4; ++r) {
                    const int kidx = k0 + kt * 16 + hi4 * 4 + r;
                    const float sv = (kidx < ncb) ? sc[kt][r] : -1e30f;
                    sc[kt][r] = sv;
                    cmax = fmaxf(cmax, sv);
                }
        }
        cmax = fmaxf(cmax, __shfl_xor(cmax, 16));
        cmax = fmaxf(cmax, __shfl_xor(cmax, 32));

        const float mnew = fmaxf(m, cmax);
        const float e1 = __expf(m - mnew);   // m=-inf pre-first-tile -> 0
        m = mnew;

        float ps = 0.f;
        #pragma unroll
        for (int kt = 0; kt < 4; ++kt) {
            const float pv0 = __expf(sc[kt][0] - mnew);  // -1e30 -> exp = 0
            const float pv1 = __expf(sc[kt][1] - mnew);
            const float pv2 = __expf(sc[kt][2] - mnew);
            const float pv3 = __expf(sc[kt][3] - mnew);
            ps += (pv0 + pv1) + (pv2 + pv3);
            const unsigned w0 = (unsigned)f2b(pv0) | ((unsigned)f2b(pv1) << 16);
            const unsigned w1 = (unsigned)f2b(pv2) | ((unsigned)f2b(pv3) << 16);
            const int blk16 = (kt * 2 + (hi4 >> 1)) ^ (lo4 & 7);
            unsigned* dst = (unsigned*)&Pw[lo4 * 64 + blk16 * 8 + (hi4 & 1) * 4];
            dst[0] = w0; dst[1] = w1;
        }
        ps += __shfl_xor(ps, 16);
        ps += __shfl_xor(ps, 32);
        l = l * e1 + ps;

        #pragma unroll
        for (int dt = 0; dt < 4; ++dt)
            #pragma unroll
            for (int r = 0; r < 4; ++r) ctx[dt][r] *= e1;

        // ctx^T += V^T . P^T  (same-wave LDS RAW: compiler orders via lgkmcnt)
        #pragma unroll
        for (int c = 0; c < 2; ++c) {
            const bf16x8 pf =
                *(bf16x8*)&Pw[lo4 * 64 + (((c * 4 + hi4) ^ (lo4 & 7)) * 8)];
            #pragma unroll
            for (int dt = 0; dt < 4; ++dt) {
                const int row = dt * 16 + lo4;
                const bf16x8 vf =
                    *(bf16x8*)&VTs[row * 64 + (((c * 4 + hi4) ^ (row & 7)) * 8)];
                ctx[dt] = __builtin_amdgcn_mfma_f32_16x16x32_bf16(vf, pf, ctx[dt], 0, 0, 0);
            }
        }

        asm volatile("s_waitcnt vmcnt(0)" ::: "memory");  // next tile landed
        __syncthreads();                                  // all waves done w/ buf
        buf ^= 1;
    }

    // epilogue: normalize, transpose via LDS (stride 68: conflict-free)
    asm volatile("s_waitcnt vmcnt(0)" ::: "memory");
    __syncthreads();
    const float inv = (l > 0.f) ? (1.f / l) : 0.f;   // l==0: fully masked -> 0
    float* OutL = (float*)SM;                        // [64 q][68] fp32
    #pragma unroll
    for (int dt = 0; dt < 4; ++dt)
        #pragma unroll
        for (int r = 0; r < 4; ++r)
            OutL[(wave * 16 + lo4) * 68 + dt * 16 + hi4 * 4 + r] = ctx[dt][r] * inv;
    __syncthreads();
    {
        const int row = tid >> 2, cb = (tid & 3) * 16;
        float* dst = CTX + ((size_t)(b * SEQ + qblk * 64 + row)) * D_MODEL
                         + h * DK + cb;
        #pragma unroll
        for (int u = 0; u < 4; ++u)
            *(float4*)&dst[u * 4] = *(float4*)&OutL[row * 68 + cb + u * 4];
    }
}

// ---------------------------------------------------------------------------
// fp32 fallback path (only if ws too small)
// ---------------------------------------------------------------------------
template <int SPLIT>
__global__ __launch_bounds__(256) void gemm_bias_kernel(
    const float* __restrict__ A, const float* __restrict__ W,
    const float* __restrict__ bias, float* __restrict__ C,
    int M, int N, int K)
{
    constexpr int TILE = 64, KT = 16;
    __shared__ float As[KT][TILE + 4];
    __shared__ float Ws[KT][TILE + 4];
    const int tid = threadIdx.x;
    const int tx = tid & 15, ty = tid >> 4;
    const int bm = blockIdx.x * TILE, bn = blockIdx.y * TILE;
    const int lrow = tid >> 2, lk4 = (tid & 3) << 2;
    float acc[4][4] = {{0.f}};
    for (int k0 = 0; k0 < K; k0 += KT) {
        const float4 a4 = *(const float4*)&A[(size_t)(bm + lrow) * K + k0 + lk4];
        const float4 w4 = *(const float4*)&W[(size_t)(bn + lrow) * K + k0 + lk4];
        __syncthreads();
        As[lk4 + 0][lrow] = a4.x; As[lk4 + 1][lrow] = a4.y;
        As[lk4 + 2][lrow] = a4.z; As[lk4 + 3][lrow] = a4.w;
        Ws[lk4 + 0][lrow] = w4.x; Ws[lk4 + 1][lrow] = w4.y;
        Ws[lk4 + 2][lrow] = w4.z; Ws[lk4 + 3][lrow] = w4.w;
        __syncthreads();
        #pragma unroll
        for (int kk = 0; kk < KT; ++kk) {
            const float4 av = *(const float4*)&As[kk][ty << 2];
            const float4 wv = *(const float4*)&Ws[kk][tx << 2];
            acc[0][0] += av.x * wv.x; acc[0][1] += av.x * wv.y; acc[0][2] += av.x * wv.z; acc[0][3] += av.x * wv.w;
            acc[1][0] += av.y * wv.x; acc[1][1] += av.y * wv.y; acc[1][2] += av.y * wv.z; acc[1][3] += av.y * wv.w;
            acc[2][0] += av.z * wv.x; acc[2][1] += av.z * wv.y; acc[2][2] += av.z * wv.z; acc[2][3] += av.z * wv.w;
            acc[3][0] += av.w * wv.x; acc[3][1] += av.w * wv.y; acc[3][2] += av.w * wv.z; acc[3][3] += av.w * wv.w;
        }
    }
    const float4 bb = *(const float4*)&bias[bn + (tx << 2)];
    #pragma unroll
    for (int i = 0; i < 4; ++i) {
        const int row = bm + (ty << 2) + i;
        float4 o;
        o.x = acc[i][0] + bb.x; o.y = acc[i][1] + bb.y;
        o.z = acc[i][2] + bb.z; o.w = acc[i][3] + bb.w;
        if (SPLIT) {
            const int b = row >> 11, s = row & (SEQ - 1), hh = bn >> 6;
            *(float4*)&C[((size_t)((b * NUM_HEADS + hh) * SEQ + s)) * DK + (tx << 2)] = o;
        } else {
            *(float4*)&C[(size_t)row * N + bn + (tx << 2)] = o;
        }
    }
}

__global__ __launch_bounds__(256, 2) void attn_fp32_kernel(
    const float* __restrict__ Q, const float* __restrict__ K,
    const float* __restrict__ V, const int* __restrict__ mask,
    float* __restrict__ OUT)
{
    const int qb = blockIdx.x, h = blockIdx.y, b = blockIdx.z;
    const int wave = threadIdx.x >> 6, lane = threadIdx.x & 63;
    const int tid = threadIdx.x;
    const int bh = b * NUM_HEADS + h;
    const float* Qb = Q + (size_t)bh * SEQ * DK;
    const float* Kb = K + (size_t)bh * SEQ * DK;
    const float* Vb = V + (size_t)bh * SEQ * DK;
    const int* mb = mask + b * SEQ;
    __shared__ float Ks[64][68];
    __shared__ float Vs[64][68];
    const int row = qb * 256 + wave * 64 + lane;
    float q[DK], ctx[DK];
    #pragma unroll
    for (int d4 = 0; d4 < 16; ++d4) {
        const float4 t = *(const float4*)&Qb[(size_t)row * DK + 4 * d4];
        q[4*d4] = t.x; q[4*d4+1] = t.y; q[4*d4+2] = t.z; q[4*d4+3] = t.w;
        ctx[4*d4] = 0.f; ctx[4*d4+1] = 0.f; ctx[4*d4+2] = 0.f; ctx[4*d4+3] = 0.f;
    }
    float m = -INFINITY, l = 0.f;
    for (int t = 0; t < SEQ / 64; ++t) {
        const int k0 = t * 64;
        const float* Kt = Kb + (size_t)k0 * DK;
        const float* Vt = Vb + (size_t)k0 * DK;
        __syncthreads();
        #pragma unroll
        for (int i = 0; i < 4; ++i) {
            const int f4 = i * 256 + tid;
            const int r = f4 >> 4, c = (f4 & 15) << 2;
            *(float4*)&Ks[r][c] = *(const float4*)&Kt[4 * f4];
            *(float4*)&Vs[r][c] = *(const float4*)&Vt[4 * f4];
        }
        __syncthreads();
        const unsigned long long mbits = __ballot(mb[k0 + lane] != 0);
        if (mbits == 0ULL) continue;
        for (int c0 = 0; c0 < 64; c0 += 16) {
            const unsigned bits = (unsigned)((mbits >> c0) & 0xFFFFULL);
            if (!bits) continue;
            float sc[16];
            #pragma unroll
            for (int j = 0; j < 16; ++j) {
                if (!((bits >> j) & 1u)) { sc[j] = -INFINITY; continue; }
                float a0 = 0.f, a1 = 0.f, a2 = 0.f, a3 = 0.f;
                #pragma unroll
                for (int d4 = 0; d4 < 16; ++d4) {
                    const float4 kv = *(const float4*)&Ks[c0 + j][4 * d4];
                    a0 += q[4*d4] * kv.x; a1 += q[4*d4+1] * kv.y;
                    a2 += q[4*d4+2] * kv.z; a3 += q[4*d4+3] * kv.w;
                }
                sc[j] = ((a0 + a1) + (a2 + a3)) * 0.125f;
            }
            float cmax = sc[0];
            #pragma unroll
            for (int j = 1; j < 16; ++j) cmax = fmaxf(cmax, sc[j]);
            if (cmax > m) {
                const float scale = __expf(m - cmax);
                l *= scale;
                #pragma unroll
                for (int d = 0; d < DK; ++d) ctx[d] *= scale;
                m = cmax;
            }
            #pragma unroll
            for (int j = 0; j < 16; ++j) {
                if (!((bits >> j) & 1u)) continue;
                const float p = __expf(sc[j] - m);
                l += p;
                #pragma unroll
                for (int d4 = 0; d4 < 16; ++d4) {
                    const float4 vv = *(const float4*)&Vs[c0 + j][4 * d4];
                    ctx[4*d4] += p * vv.x; ctx[4*d4+1] += p * vv.y;
                    ctx[4*d4+2] += p * vv.z; ctx[4*d4+3] += p * vv.w;
                }
            }
        }
    }
    const float inv = (l > 0.f) ? (1.f / l) : 0.f;
    float* dst = OUT + ((size_t)(b * SEQ + row)) * D_MODEL + h * DK;
    #pragma unroll
    for (int d4 = 0; d4 < 16; ++d4) {
        float4 o;
        o.x = ctx[4*d4] * inv; o.y = ctx[4*d4+1] * inv;
        o.z = ctx[4*d4+2] * inv; o.w = ctx[4*d4+3] * inv;
        *(float4*)&dst[4 * d4] = o;
    }
}

// ---------------------------------------------------------------------------
extern "C" void kernel_launch(void* const* d_in, const int* in_sizes, int n_in,
                              void* d_out, int out_size, void* d_ws, size_t ws_size,
                              hipStream_t stream)
{
    const float* query = (const float*)d_in[0];
    const float* key_  = (const float*)d_in[1];
    const float* value = (const float*)d_in[2];
    const int*   mask  = (const int*)d_in[3];
    const float* Wq = (const float*)d_in[4];
    const float* bq = (const float*)d_in[5];
    const float* Wk = (const float*)d_in[6];
    const float* bk = (const float*)d_in[7];
    const float* Wv = (const float*)d_in[8];
    const float* bv = (const float*)d_in[9];
    const float* Wo = (const float*)d_in[10];
    const float* bo = (const float*)d_in[11];
    float* out = (float*)d_out;

    const int M = BATCH * SEQ;                            // 4096
    const size_t PER_B  = (size_t)M * D_MODEL * 4;        // 16 MB
    const size_t ACT_B  = (size_t)M * 2048 * 2;           // 16 MB bf16 [hi|lo]
    const size_t W2_B   = (size_t)D_MODEL * 2048 * 2;     // 4 MB
    const size_t K2_B   = (size_t)32 * SEQ * 128 * 2;     // 16.8 MB
    const size_t VT2_B  = (size_t)32 * DK * SEQ * 2;      // 8.4 MB
    const size_t POS_B  = (size_t)BATCH * SEQ * 4 + 256;

    char* base = (char*)d_ws;
    float* q_ws = (float*)(base);
    float* c_ws = (float*)(base + PER_B);
    unsigned short* actA = (unsigned short*)(base + 2 * PER_B);
    unsigned short* actB = (unsigned short*)((char*)actA + ACT_B);
    unsigned short* w2q = (unsigned short*)((char*)actB + ACT_B);
    unsigned short* w2k = (unsigned short*)((char*)w2q + W2_B);
    unsigned short* w2v = (unsigned short*)((char*)w2k + W2_B);
    unsigned short* w2o = (unsigned short*)((char*)w2v + W2_B);
    unsigned short* k2  = (unsigned short*)((char*)w2o + W2_B);
    unsigned short* vt2 = (unsigned short*)((char*)k2 + K2_B);
    int* posArr = (int*)((char*)vt2 + VT2_B);
    int* ncArr  = posArr + BATCH * SEQ;
    const size_t need = 2 * PER_B + 2 * ACT_B + 4 * W2_B + K2_B + VT2_B + POS_B;

    if (ws_size >= need) {      // ~106 MB
        mask_scan_kernel<<<BATCH, 256, 0, stream>>>(mask, posArr, ncArr);
        hipMemsetAsync(k2, 0, K2_B, stream);
        hipMemsetAsync(vt2, 0, VT2_B, stream);

        // all 4 weight conversions in one dispatch
        conv_hilo_kernel<<<dim3(D_MODEL, 4), 256, 0, stream>>>(
            Wq, Wk, Wv, Wo, w2q, w2k, w2v, w2o, D_MODEL);

        // K & V chains merged
        conv_hilo_kernel<<<dim3(M, 2), 256, 0, stream>>>(
            key_, value, nullptr, nullptr, actA, actB, nullptr, nullptr, M);
        mfma_gemm_kv_kernel<<<dim3(M / 128, D_MODEL / 64, 2), 256, 0, stream>>>(
            actA, actB, w2k, w2v, bk, bv, k2, vt2, mask, posArr);

        // Q chain (actA free after gemmKV)
        conv_hilo_kernel<<<dim3(M, 1), 256, 0, stream>>>(
            query, nullptr, nullptr, nullptr, actA, nullptr, nullptr, nullptr, M);
        mfma_gemm_kernel<1><<<dim3(M / 128, D_MODEL / 64), 256, 0, stream>>>(
            actA, w2q, bq, q_ws);

        attn_mfma_kernel<<<1024, 256, 0, stream>>>(q_ws, k2, vt2, ncArr, c_ws);

        // output chain
        conv_hilo_kernel<<<dim3(M, 1), 256, 0, stream>>>(
            c_ws, nullptr, nullptr, nullptr, actA, nullptr, nullptr, nullptr, M);
        mfma_gemm_kernel<0><<<dim3(M / 128, D_MODEL / 64), 256, 0, stream>>>(
            actA, w2o, bo, out);
    } else {
        float* k_ws = (float*)(base + 2 * PER_B);
        float* v_ws = (float*)(base + 3 * PER_B);
        dim3 ggrid(M / 64, D_MODEL / 64);
        gemm_bias_kernel<1><<<ggrid, 256, 0, stream>>>(query, Wq, bq, q_ws, M, D_MODEL, D_MODEL);
        gemm_bias_kernel<1><<<ggrid, 256, 0, stream>>>(key_,  Wk, bk, k_ws, M, D_MODEL, D_MODEL);
        gemm_bias_kernel<1><<<ggrid, 256, 0, stream>>>(value, Wv, bv, v_ws, M, D_MODEL, D_MODEL);
        dim3 agrid(SEQ / 256, NUM_HEADS, BATCH);
        attn_fp32_kernel<<<agrid, 256, 0, stream>>>(q_ws, k_ws, v_ws, mask, c_ws);
        gemm_bias_kernel<0><<<ggrid, 256, 0, stream>>>(c_ws, Wo, bo, out, M, D_MODEL, D_MODEL);
    }
}

// Round 9
// 298.778 us; speedup vs baseline: 1.1188x; 1.1188x over previous
//
#include <hip/hip_runtime.h>
#include <math.h>

#define D_MODEL 1024
#define NUM_HEADS 16
#define DK 64
#define BATCH 2
#define SEQ 2048

using f32x4  = __attribute__((ext_vector_type(4))) float;
using bf16x8 = __attribute__((ext_vector_type(8))) short;
using us8    = __attribute__((ext_vector_type(8))) unsigned short;

__device__ __forceinline__ unsigned short f2b(float x) {  // fp32 -> bf16 RNE
    unsigned u = __float_as_uint(x);
    return (unsigned short)((u + 0x7FFF + ((u >> 16) & 1)) >> 16);
}
__device__ __forceinline__ float b2f(unsigned short h) {
    return __uint_as_float(((unsigned)h) << 16);
}
__device__ __forceinline__ void gl_lds16(const unsigned short* g, unsigned short* l) {
    __builtin_amdgcn_global_load_lds(
        (const __attribute__((address_space(1))) void*)g,
        (__attribute__((address_space(3))) void*)l, 16, 0, 0);
}

// ---------------------------------------------------------------------------
// Per-batch prefix scan of mask: pos[b][s] = #valid keys before s, nc[b]=count
// ---------------------------------------------------------------------------
__global__ __launch_bounds__(256) void mask_scan_kernel(
    const int* __restrict__ mask, int* __restrict__ pos, int* __restrict__ nc)
{
    const int b = blockIdx.x;
    const int tid = threadIdx.x;
    __shared__ int sums[256];
    int v[8]; int cnt = 0;
    const int base = b * SEQ + tid * 8;
    #pragma unroll
    for (int e = 0; e < 8; ++e) { v[e] = (mask[base + e] != 0) ? 1 : 0; cnt += v[e]; }
    sums[tid] = cnt;
    __syncthreads();
    for (int off = 1; off < 256; off <<= 1) {
        int t = (tid >= off) ? sums[tid - off] : 0;
        __syncthreads();
        sums[tid] += t;
        __syncthreads();
    }
    int run = sums[tid] - cnt;           // exclusive prefix
    #pragma unroll
    for (int e = 0; e < 8; ++e) { pos[base + e] = run; run += v[e]; }
    if (tid == 255) nc[b] = sums[255];
}

// ---------------------------------------------------------------------------
// fp32 [rows][1024] -> bf16 [rows][2048] = [hi | lo] along K, row-XOR swizzle
// baked in (stored 16B block ss holds logical block ss ^ (row&7) per 64-col
// group). Up to 4 (src,dst) pairs via blockIdx.y; grid.x = rows.
// ---------------------------------------------------------------------------
__global__ __launch_bounds__(256) void conv_hilo_kernel(
    const float* s0, const float* s1, const float* s2, const float* s3,
    unsigned short* d0, unsigned short* d1, unsigned short* d2, unsigned short* d3,
    int rows)
{
    const int y = blockIdx.y;
    const float* src = (y == 0) ? s0 : (y == 1) ? s1 : (y == 2) ? s2 : s3;
    unsigned short* dst = (y == 0) ? d0 : (y == 1) ? d1 : (y == 2) ? d2 : d3;
    const int id = blockIdx.x * 256 + threadIdx.x;
    if (id >= rows * 256) return;
    const int row = id >> 8;
    const int s   = id & 255;                // stored 16B-block index in [0,256)
    const int g   = s >> 3, ss = s & 7;
    const int lb  = ss ^ (row & 7);          // logical block within 64-col group
    const int srcg = g & 15;                 // source 64-col group
    const bool lo = (g >> 4) != 0;           // second K-half = residual

    const float* p = src + (size_t)row * 1024 + srcg * 64 + lb * 8;
    const float4 a = *(const float4*)p;
    const float4 bq = *(const float4*)(p + 4);
    const float xs[8] = {a.x, a.y, a.z, a.w, bq.x, bq.y, bq.z, bq.w};
    us8 o;
    #pragma unroll
    for (int e = 0; e < 8; ++e) {
        float x = xs[e];
        if (lo) { unsigned short h = f2b(x); x = x - b2f(h); }
        o[e] = f2b(x);
    }
    *(us8*)&dst[(size_t)row * 2048 + s * 8] = o;
}

// ---------------------------------------------------------------------------
// bf16 MFMA GEMM, 128x128 tile (r5-proven fragment math), virtual-K sweep of
// 48 tiles over [hi|lo] operands (3-term hi/lo product, r8-proven):
//   vkt 0-15: Ahi*Whi   16-31: Alo*Whi   32-47: Ahi*Wlo
// NEW: 4-deep LDS rotation (128 KB) + counted vmcnt + RAW s_barrier (not
// __syncthreads -> no vmcnt(0) drain) — loads fly 3 tiles (~750 cy) ahead.
// MODE epilogue:
//   0: fp32 [M][1024]  (output GEMM -> d_out)
//   1: Q2  bf16 [bh][s][128] = 0.125*(hi|lo), block-XOR by s&7
//   2: K2  bf16 [bh][kpos][128] hi|lo, COMPACTED via pos[], masked skip
//   3: VT2 bf16 [bh][d][2048], key-block swizzle, COMPACTED via pos[]
// ---------------------------------------------------------------------------
template <int MODE>
__global__ __launch_bounds__(256) void mfma_gemm_kernel(
    const unsigned short* __restrict__ A2, const unsigned short* __restrict__ W2,
    const float* __restrict__ bias, float* __restrict__ Cf,
    unsigned short* __restrict__ Cb,
    const int* __restrict__ mask, const int* __restrict__ pos)
{
    constexpr int KS = 2048;
    __shared__ bf16x8 Asl[4][1024];   // 4 bufs x 128 rows x 8 x 16B = 64 KB
    __shared__ bf16x8 Bsl[4][1024];   // 64 KB

    const int tid = threadIdx.x;
    const int wv = tid >> 6, ln = tid & 63;
    const int wm = wv >> 1, wn = wv & 1;
    const int bm = blockIdx.x * 128, bn = blockIdx.y * 128;
    const int x = ln & 15, y = ln >> 4;

    f32x4 acc[4][4] = {};

    const unsigned short* Ab = A2 + (size_t)bm * KS;
    const unsigned short* Bb = W2 + (size_t)bn * KS;
    const int srow = ln >> 3;
    const int scol = (ln & 7) * 8;

    auto stage = [&](int bufi, int vkt) {    // 8 per-wave gl_lds per stage
        const int a_kt = (vkt < 32) ? vkt : vkt - 32;
        const int w_kt = (vkt < 32) ? (vkt & 15) : vkt - 16;
        #pragma unroll
        for (int c = 0; c < 4; ++c) {
            const int rowb = wv * 32 + c * 8;
            gl_lds16(Ab + (size_t)(rowb + srow) * KS + a_kt * 64 + scol,
                     (unsigned short*)&Asl[bufi][rowb << 3]);
            gl_lds16(Bb + (size_t)(rowb + srow) * KS + w_kt * 64 + scol,
                     (unsigned short*)&Bsl[bufi][rowb << 3]);
        }
    };

    stage(0, 0); stage(1, 1); stage(2, 2);   // 24 per-wave loads in flight

    for (int t = 0; t < 48; ++t) {
        // retire tile t's 8 loads (oldest); keep t+1,t+2(,t+3) in flight
        if (t < 46)       asm volatile("s_waitcnt vmcnt(16)" ::: "memory");
        else if (t == 46) asm volatile("s_waitcnt vmcnt(8)" ::: "memory");
        else              asm volatile("s_waitcnt vmcnt(0)" ::: "memory");
        __builtin_amdgcn_s_barrier();        // raw: does NOT drain vmcnt
        __builtin_amdgcn_sched_barrier(0);   // pin: nothing crosses
        if (t + 3 < 48) stage((t + 3) & 3, t + 3);
        const int buf = t & 3;
        #pragma unroll
        for (int half = 0; half < 2; ++half) {
            bf16x8 af[4], bfr[4];
            #pragma unroll
            for (int mf = 0; mf < 4; ++mf) {
                const int r = wm * 64 + mf * 16 + x;
                af[mf] = Asl[buf][(r << 3) | ((half * 4 + y) ^ (r & 7))];
            }
            #pragma unroll
            for (int nf = 0; nf < 4; ++nf) {
                const int r = wn * 64 + nf * 16 + x;
                bfr[nf] = Bsl[buf][(r << 3) | ((half * 4 + y) ^ (r & 7))];
            }
            #pragma unroll
            for (int mf = 0; mf < 4; ++mf)
                #pragma unroll
                for (int nf = 0; nf < 4; ++nf)
                    acc[mf][nf] = __builtin_amdgcn_mfma_f32_16x16x32_bf16(
                        af[mf], bfr[nf], acc[mf][nf], 0, 0, 0);
        }
    }

    // epilogue: C/D layout col=lane&15 (n), row=(lane>>4)*4+r (m)  [m89]
    #pragma unroll
    for (int nf = 0; nf < 4; ++nf) {
        const int n = bn + wn * 64 + nf * 16 + x;
        const float bv = bias[n];
        #pragma unroll
        for (int mf = 0; mf < 4; ++mf) {
            const int mbase = bm + wm * 64 + mf * 16 + y * 4;
            #pragma unroll
            for (int r = 0; r < 4; ++r) {
                const int m = mbase + r;
                const float v = acc[mf][nf][r] + bv;
                const int b = m >> 11, s = m & (SEQ - 1);
                const int hh = n >> 6, dd = n & 63;
                if (MODE == 0) {
                    Cf[(size_t)m * D_MODEL + n] = v;
                } else if (MODE == 1) {
                    // Q2: scaled hi|lo, same swizzle as K2 but keyed by s
                    const float sv = v * 0.125f;
                    const unsigned short hi = f2b(sv);
                    const unsigned short lo = f2b(sv - b2f(hi));
                    const int blk = (dd >> 3) ^ (s & 7), i = dd & 7;
                    unsigned short* qp = Cb +
                        ((size_t)((b * NUM_HEADS + hh) * SEQ + s)) * 128;
                    qp[blk * 8 + i] = hi;
                    qp[64 + blk * 8 + i] = lo;
                } else if (MODE == 2) {
                    if (mask[b * SEQ + s]) {
                        const int p = pos[b * SEQ + s];
                        const unsigned short hi = f2b(v);
                        const unsigned short lo = f2b(v - b2f(hi));
                        const int blk = (dd >> 3) ^ (p & 7), i = dd & 7;
                        unsigned short* kp = Cb +
                            ((size_t)((b * NUM_HEADS + hh) * SEQ + p)) * 128;
                        kp[blk * 8 + i] = hi;
                        kp[64 + blk * 8 + i] = lo;
                    }
                } else {
                    if (mask[b * SEQ + s]) {
                        const int p = pos[b * SEQ + s];
                        const int tile = p >> 6, w = p & 63;
                        const int blk = (w >> 3) ^ (dd & 7), i = w & 7;
                        Cb[((size_t)((b * NUM_HEADS + hh) * DK + dd)) * SEQ +
                           tile * 64 + blk * 8 + i] = f2b(v);
                    }
                }
            }
        }
    }
}

// ---------------------------------------------------------------------------
// MFMA flash attention over COMPACTED keys (r7-proven structure: single
// 32 KB buffer, 4 blocks/CU). Q read pre-converted (Q2). Output fused:
// epilogue writes the bf16 [hi|lo] row-XOR-swizzled activation directly.
// ---------------------------------------------------------------------------
__global__ __launch_bounds__(256, 3) void attn_mfma_kernel(
    const unsigned short* __restrict__ Q2, const unsigned short* __restrict__ K2,
    const unsigned short* __restrict__ VT2, const int* __restrict__ ncArr,
    unsigned short* __restrict__ ACT)
{
    __shared__ __align__(16) unsigned short SM[16384];   // 32 KB
    unsigned short* Khi = SM;            // [64 key][64 dk] (swz)
    unsigned short* Klo = SM + 4096;
    unsigned short* VTs = SM + 8192;     // [64 d][64 key] (swz)

    const int tid = threadIdx.x;
    const int wave = tid >> 6, lane = tid & 63;
    const int lo4 = lane & 15, hi4 = lane >> 4;
    unsigned short* Pw = SM + 12288 + wave * 1024;  // [16 q][64 key] bf16

    const int orig = blockIdx.x;
    const int swz = (orig & 7) * 128 + (orig >> 3);  // 1024%8==0: bijective
    const int bh = swz >> 5, qblk = swz & 31;
    const int b = bh >> 4, h = bh & 15;

    const unsigned short* Kb = K2 + (size_t)bh * SEQ * 128;
    const unsigned short* Vb = VT2 + (size_t)bh * DK * SEQ;

    const int ncb = ncArr[b];
    const int ntiles = (ncb + 63) >> 6;

    // Q fragments from Q2 (already 0.125-scaled hi/lo, XOR-swizzled by s&7)
    const int qr = qblk * 64 + wave * 16 + lo4;
    const unsigned short* Q2row = Q2 + (size_t)(bh * SEQ + qr) * 128;
    bf16x8 qhi[2], qlo[2];
    #pragma unroll
    for (int c = 0; c < 2; ++c) {
        const int blk = ((c * 4 + hi4) ^ (qr & 7)) * 8;
        qhi[c] = *(const bf16x8*)&Q2row[blk];
        qlo[c] = *(const bf16x8*)&Q2row[64 + blk];
    }

    f32x4 ctx[4] = {};   // ctx^T frags: row d = dt*16+hi4*4+r, col q = lo4
    float m = -INFINITY, l = 0.f;

    for (int t = 0; t < ntiles; ++t) {
        const int k0 = t * 64;
        __syncthreads();
        // stage 24 KB: Khi(512 x16B) | Klo(512) | VT(512)
        #pragma unroll
        for (int j = 0; j < 6; ++j) {
            const int g = j * 256 + wave * 64;   // wave-uniform dest base
            const int gi = g + lane;
            const unsigned short* src;
            if (gi < 512) {
                src = Kb + (size_t)(k0 + (gi >> 3)) * 128 + (gi & 7) * 8;
            } else if (gi < 1024) {
                const int g2 = gi - 512;
                src = Kb + (size_t)(k0 + (g2 >> 3)) * 128 + 64 + (g2 & 7) * 8;
            } else {
                const int g3 = gi - 1024;
                src = Vb + (size_t)(g3 >> 3) * SEQ + k0 + (g3 & 7) * 8;
            }
            gl_lds16(src, SM + (size_t)g * 8);
        }
        asm volatile("s_waitcnt vmcnt(0)" ::: "memory");
        __syncthreads();

        // S^T = K . Q^T : rows = key, cols = q (hi/lo 3-term, fp32-accurate)
        f32x4 sc[4];
        #pragma unroll
        for (int kt = 0; kt < 4; ++kt) {
            f32x4 s = {0.f, 0.f, 0.f, 0.f};
            const int row = kt * 16 + lo4;
            const int rx = row & 7;
            #pragma unroll
            for (int c = 0; c < 2; ++c) {
                const int blk = ((c * 4 + hi4) ^ rx) * 8;
                const bf16x8 kh = *(bf16x8*)&Khi[row * 64 + blk];
                const bf16x8 kl = *(bf16x8*)&Klo[row * 64 + blk];
                s = __builtin_amdgcn_mfma_f32_16x16x32_bf16(kh, qhi[c], s, 0, 0, 0);
                s = __builtin_amdgcn_mfma_f32_16x16x32_bf16(kl, qhi[c], s, 0, 0, 0);
                s = __builtin_amdgcn_mfma_f32_16x16x32_bf16(kh, qlo[c], s, 0, 0, 0);
            }
            sc[kt] = s;
        }

        // row-max; tail tile masks invalid keys (kidx >= ncb) to -1e30
        float cmax = -1e30f;
        if (k0 + 64 <= ncb) {
            #pragma unroll
            for (int kt = 0; kt < 4; ++kt)
                #pragma unroll
                for (int r = 0; r < 4; ++r) cmax = fmaxf(cmax, sc[kt][r]);
        } else {
            #pragma unroll
            for (int kt = 0; kt < 4; ++kt)
                #pragma unroll
                for (int r = 0; r < 4; ++r) {
                    const int kidx = k0 + kt * 16 + hi4 * 4 + r;
                    const float sv = (kidx < ncb) ? sc[kt][r] : -1e30f;
                    sc[kt][r] = sv;
                    cmax = fmaxf(cmax, sv);
                }
        }
        cmax = fmaxf(cmax, __shfl_xor(cmax, 16));
        cmax = fmaxf(cmax, __shfl_xor(cmax, 32));

        const float mnew = fmaxf(m, cmax);
        const float e1 = __expf(m - mnew);   // m=-inf pre-first-tile -> 0
        m = mnew;

        float ps = 0.f;
        #pragma unroll
        for (int kt = 0; kt < 4; ++kt) {
            const float pv0 = __expf(sc[kt][0] - mnew);  // -1e30 -> exp = 0
            const float pv1 = __expf(sc[kt][1] - mnew);
            const float pv2 = __expf(sc[kt][2] - mnew);
            const float pv3 = __expf(sc[kt][3] - mnew);
            ps += (pv0 + pv1) + (pv2 + pv3);
            const unsigned w0 = (unsigned)f2b(pv0) | ((unsigned)f2b(pv1) << 16);
            const unsigned w1 = (unsigned)f2b(pv2) | ((unsigned)f2b(pv3) << 16);
            const int blk16 = (kt * 2 + (hi4 >> 1)) ^ (lo4 & 7);
            unsigned* dst = (unsigned*)&Pw[lo4 * 64 + blk16 * 8 + (hi4 & 1) * 4];
            dst[0] = w0; dst[1] = w1;
        }
        ps += __shfl_xor(ps, 16);
        ps += __shfl_xor(ps, 32);
        l = l * e1 + ps;

        #pragma unroll
        for (int dt = 0; dt < 4; ++dt)
            #pragma unroll
            for (int r = 0; r < 4; ++r) ctx[dt][r] *= e1;

        // ctx^T += V^T . P^T  (same-wave LDS RAW: compiler orders via lgkmcnt)
        #pragma unroll
        for (int c = 0; c < 2; ++c) {
            const bf16x8 pf =
                *(bf16x8*)&Pw[lo4 * 64 + (((c * 4 + hi4) ^ (lo4 & 7)) * 8)];
            #pragma unroll
            for (int dt = 0; dt < 4; ++dt) {
                const int row = dt * 16 + lo4;
                const bf16x8 vf =
                    *(bf16x8*)&VTs[row * 64 + (((c * 4 + hi4) ^ (row & 7)) * 8)];
                ctx[dt] = __builtin_amdgcn_mfma_f32_16x16x32_bf16(vf, pf, ctx[dt], 0, 0, 0);
            }
        }
    }

    // epilogue: normalize, transpose via LDS (stride 68, conflict-free),
    // FUSED bf16 [hi|lo] swizzled activation write (skips c_ws + O-conv)
    __syncthreads();
    const float inv = (l > 0.f) ? (1.f / l) : 0.f;   // l==0: fully masked -> 0
    float* OutL = (float*)SM;                        // [64 q][68] fp32
    #pragma unroll
    for (int dt = 0; dt < 4; ++dt)
        #pragma unroll
        for (int r = 0; r < 4; ++r)
            OutL[(wave * 16 + lo4) * 68 + dt * 16 + hi4 * 4 + r] = ctx[dt][r] * inv;
    __syncthreads();
    {
        const int row = tid >> 2, cb = (tid & 3) * 16;
        const int mrow = b * SEQ + qblk * 64 + row;      // global act row
        unsigned short* arow = ACT + (size_t)mrow * 2048;
        #pragma unroll
        for (int u = 0; u < 2; ++u) {
            const int lb = (cb >> 3) + u;                // logical 8-col block
            const int ss = lb ^ (mrow & 7);              // stored (swizzled)
            us8 hv, lv;
            #pragma unroll
            for (int i = 0; i < 8; ++i) {
                const float v = OutL[row * 68 + cb + u * 8 + i];
                const unsigned short hb = f2b(v);
                hv[i] = (short)hb;
                lv[i] = (short)f2b(v - b2f(hb));
            }
            *(us8*)&arow[h * 64 + ss * 8] = hv;          // hi half (group h)
            *(us8*)&arow[1024 + h * 64 + ss * 8] = lv;   // lo half
        }
    }
}

// ---------------------------------------------------------------------------
// fp32 fallback path (only if ws too small)
// ---------------------------------------------------------------------------
template <int SPLIT>
__global__ __launch_bounds__(256) void gemm_bias_kernel(
    const float* __restrict__ A, const float* __restrict__ W,
    const float* __restrict__ bias, float* __restrict__ C,
    int M, int N, int K)
{
    constexpr int TILE = 64, KT = 16;
    __shared__ float As[KT][TILE + 4];
    __shared__ float Ws[KT][TILE + 4];
    const int tid = threadIdx.x;
    const int tx = tid & 15, ty = tid >> 4;
    const int bm = blockIdx.x * TILE, bn = blockIdx.y * TILE;
    const int lrow = tid >> 2, lk4 = (tid & 3) << 2;
    float acc[4][4] = {{0.f}};
    for (int k0 = 0; k0 < K; k0 += KT) {
        const float4 a4 = *(const float4*)&A[(size_t)(bm + lrow) * K + k0 + lk4];
        const float4 w4 = *(const float4*)&W[(size_t)(bn + lrow) * K + k0 + lk4];
        __syncthreads();
        As[lk4 + 0][lrow] = a4.x; As[lk4 + 1][lrow] = a4.y;
        As[lk4 + 2][lrow] = a4.z; As[lk4 + 3][lrow] = a4.w;
        Ws[lk4 + 0][lrow] = w4.x; Ws[lk4 + 1][lrow] = w4.y;
        Ws[lk4 + 2][lrow] = w4.z; Ws[lk4 + 3][lrow] = w4.w;
        __syncthreads();
        #pragma unroll
        for (int kk = 0; kk < KT; ++kk) {
            const float4 av = *(const float4*)&As[kk][ty << 2];
            const float4 wv = *(const float4*)&Ws[kk][tx << 2];
            acc[0][0] += av.x * wv.x; acc[0][1] += av.x * wv.y; acc[0][2] += av.x * wv.z; acc[0][3] += av.x * wv.w;
            acc[1][0] += av.y * wv.x; acc[1][1] += av.y * wv.y; acc[1][2] += av.y * wv.z; acc[1][3] += av.y * wv.w;
            acc[2][0] += av.z * wv.x; acc[2][1] += av.z * wv.y; acc[2][2] += av.z * wv.z; acc[2][3] += av.z * wv.w;
            acc[3][0] += av.w * wv.x; acc[3][1] += av.w * wv.y; acc[3][2] += av.w * wv.z; acc[3][3] += av.w * wv.w;
        }
    }
    const float4 bb = *(const float4*)&bias[bn + (tx << 2)];
    #pragma unroll
    for (int i = 0; i < 4; ++i) {
        const int row = bm + (ty << 2) + i;
        float4 o;
        o.x = acc[i][0] + bb.x; o.y = acc[i][1] + bb.y;
        o.z = acc[i][2] + bb.z; o.w = acc[i][3] + bb.w;
        if (SPLIT) {
            const int b = row >> 11, s = row & (SEQ - 1), hh = bn >> 6;
            *(float4*)&C[((size_t)((b * NUM_HEADS + hh) * SEQ + s)) * DK + (tx << 2)] = o;
        } else {
            *(float4*)&C[(size_t)row * N + bn + (tx << 2)] = o;
        }
    }
}

__global__ __launch_bounds__(256, 2) void attn_fp32_kernel(
    const float* __restrict__ Q, const float* __restrict__ K,
    const float* __restrict__ V, const int* __restrict__ mask,
    float* __restrict__ OUT)
{
    const int qb = blockIdx.x, h = blockIdx.y, b = blockIdx.z;
    const int wave = threadIdx.x >> 6, lane = threadIdx.x & 63;
    const int tid = threadIdx.x;
    const int bh = b * NUM_HEADS + h;
    const float* Qb = Q + (size_t)bh * SEQ * DK;
    const float* Kb = K + (size_t)bh * SEQ * DK;
    const float* Vb = V + (size_t)bh * SEQ * DK;
    const int* mb = mask + b * SEQ;
    __shared__ float Ks[64][68];
    __shared__ float Vs[64][68];
    const int row = qb * 256 + wave * 64 + lane;
    float q[DK], ctx[DK];
    #pragma unroll
    for (int d4 = 0; d4 < 16; ++d4) {
        const float4 t = *(const float4*)&Qb[(size_t)row * DK + 4 * d4];
        q[4*d4] = t.x; q[4*d4+1] = t.y; q[4*d4+2] = t.z; q[4*d4+3] = t.w;
        ctx[4*d4] = 0.f; ctx[4*d4+1] = 0.f; ctx[4*d4+2] = 0.f; ctx[4*d4+3] = 0.f;
    }
    float m = -INFINITY, l = 0.f;
    for (int t = 0; t < SEQ / 64; ++t) {
        const int k0 = t * 64;
        const float* Kt = Kb + (size_t)k0 * DK;
        const float* Vt = Vb + (size_t)k0 * DK;
        __syncthreads();
        #pragma unroll
        for (int i = 0; i < 4; ++i) {
            const int f4 = i * 256 + tid;
            const int r = f4 >> 4, c = (f4 & 15) << 2;
            *(float4*)&Ks[r][c] = *(const float4*)&Kt[4 * f4];
            *(float4*)&Vs[r][c] = *(const float4*)&Vt[4 * f4];
        }
        __syncthreads();
        const unsigned long long mbits = __ballot(mb[k0 + lane] != 0);
        if (mbits == 0ULL) continue;
        for (int c0 = 0; c0 < 64; c0 += 16) {
            const unsigned bits = (unsigned)((mbits >> c0) & 0xFFFFULL);
            if (!bits) continue;
            float sc[16];
            #pragma unroll
            for (int j = 0; j < 16; ++j) {
                if (!((bits >> j) & 1u)) { sc[j] = -INFINITY; continue; }
                float a0 = 0.f, a1 = 0.f, a2 = 0.f, a3 = 0.f;
                #pragma unroll
                for (int d4 = 0; d4 < 16; ++d4) {
                    const float4 kv = *(const float4*)&Ks[c0 + j][4 * d4];
                    a0 += q[4*d4] * kv.x; a1 += q[4*d4+1] * kv.y;
                    a2 += q[4*d4+2] * kv.z; a3 += q[4*d4+3] * kv.w;
                }
                sc[j] = ((a0 + a1) + (a2 + a3)) * 0.125f;
            }
            float cmax = sc[0];
            #pragma unroll
            for (int j = 1; j < 16; ++j) cmax = fmaxf(cmax, sc[j]);
            if (cmax > m) {
                const float scale = __expf(m - cmax);
                l *= scale;
                #pragma unroll
                for (int d = 0; d < DK; ++d) ctx[d] *= scale;
                m = cmax;
            }
            #pragma unroll
            for (int j = 0; j < 16; ++j) {
                if (!((bits >> j) & 1u)) continue;
                const float p = __expf(sc[j] - m);
                l += p;
                #pragma unroll
                for (int d4 = 0; d4 < 16; ++d4) {
                    const float4 vv = *(const float4*)&Vs[c0 + j][4 * d4];
                    ctx[4*d4] += p * vv.x; ctx[4*d4+1] += p * vv.y;
                    ctx[4*d4+2] += p * vv.z; ctx[4*d4+3] += p * vv.w;
                }
            }
        }
    }
    const float inv = (l > 0.f) ? (1.f / l) : 0.f;
    float* dst = OUT + ((size_t)(b * SEQ + row)) * D_MODEL + h * DK;
    #pragma unroll
    for (int d4 = 0; d4 < 16; ++d4) {
        float4 o;
        o.x = ctx[4*d4] * inv; o.y = ctx[4*d4+1] * inv;
        o.z = ctx[4*d4+2] * inv; o.w = ctx[4*d4+3] * inv;
        *(float4*)&dst[4 * d4] = o;
    }
}

// ---------------------------------------------------------------------------
extern "C" void kernel_launch(void* const* d_in, const int* in_sizes, int n_in,
                              void* d_out, int out_size, void* d_ws, size_t ws_size,
                              hipStream_t stream)
{
    const float* query = (const float*)d_in[0];
    const float* key_  = (const float*)d_in[1];
    const float* value = (const float*)d_in[2];
    const int*   mask  = (const int*)d_in[3];
    const float* Wq = (const float*)d_in[4];
    const float* bq = (const float*)d_in[5];
    const float* Wk = (const float*)d_in[6];
    const float* bk = (const float*)d_in[7];
    const float* Wv = (const float*)d_in[8];
    const float* bv = (const float*)d_in[9];
    const float* Wo = (const float*)d_in[10];
    const float* bo = (const float*)d_in[11];
    float* out = (float*)d_out;

    const int M = BATCH * SEQ;                            // 4096
    const size_t ACT_B  = (size_t)M * 2048 * 2;           // 16.78 MB
    const size_t W2_B   = (size_t)D_MODEL * 2048 * 2;     // 4.19 MB
    const size_t K2_B   = (size_t)32 * SEQ * 128 * 2;     // 16.78 MB
    const size_t VT2_B  = (size_t)32 * DK * SEQ * 2;      // 8.39 MB
    const size_t Q2_B   = K2_B;                           // 16.78 MB
    const size_t POS_B  = (size_t)BATCH * SEQ * 4 + 256;

    char* base = (char*)d_ws;
    unsigned short* actQ = (unsigned short*)(base);
    unsigned short* actK = (unsigned short*)(base + ACT_B);
    unsigned short* actV = (unsigned short*)(base + 2 * ACT_B);
    unsigned short* w2q  = (unsigned short*)(base + 3 * ACT_B);
    unsigned short* w2k  = (unsigned short*)((char*)w2q + W2_B);
    unsigned short* w2v  = (unsigned short*)((char*)w2k + W2_B);
    unsigned short* w2o  = (unsigned short*)((char*)w2v + W2_B);
    unsigned short* k2   = (unsigned short*)((char*)w2o + W2_B);
    unsigned short* vt2  = (unsigned short*)((char*)k2 + K2_B);
    unsigned short* q2   = (unsigned short*)((char*)vt2 + VT2_B);
    int* posArr = (int*)((char*)q2 + Q2_B);
    int* ncArr  = posArr + BATCH * SEQ;
    const size_t need = 3 * ACT_B + 4 * W2_B + K2_B + VT2_B + Q2_B + POS_B; // ~109 MB

    if (ws_size >= need) {
        mask_scan_kernel<<<BATCH, 256, 0, stream>>>(mask, posArr, ncArr);

        conv_hilo_kernel<<<dim3(D_MODEL, 4), 256, 0, stream>>>(
            Wq, Wk, Wv, Wo, w2q, w2k, w2v, w2o, D_MODEL);
        conv_hilo_kernel<<<dim3(M, 3), 256, 0, stream>>>(
            query, key_, value, nullptr, actQ, actK, actV, nullptr, M);

        dim3 ggrid(M / 128, D_MODEL / 128);               // 32 x 8 = 256 blocks
        mfma_gemm_kernel<2><<<ggrid, 256, 0, stream>>>(
            actK, w2k, bk, nullptr, k2, mask, posArr);
        mfma_gemm_kernel<3><<<ggrid, 256, 0, stream>>>(
            actV, w2v, bv, nullptr, vt2, mask, posArr);
        mfma_gemm_kernel<1><<<ggrid, 256, 0, stream>>>(
            actQ, w2q, bq, nullptr, q2, nullptr, nullptr);

        // attn writes the O-GEMM activation (actK is dead) directly as hi|lo
        attn_mfma_kernel<<<1024, 256, 0, stream>>>(q2, k2, vt2, ncArr, actK);

        mfma_gemm_kernel<0><<<ggrid, 256, 0, stream>>>(
            actK, w2o, bo, out, nullptr, nullptr, nullptr);
    } else {
        float* q_ws = (float*)(base);
        float* k_ws = (float*)(base + (size_t)M * D_MODEL * 4);
        float* v_ws = (float*)(base + 2 * (size_t)M * D_MODEL * 4);
        float* c_ws = (float*)(base + 3 * (size_t)M * D_MODEL * 4);
        dim3 ggrid(M / 64, D_MODEL / 64);
        gemm_bias_kernel<1><<<ggrid, 256, 0, stream>>>(query, Wq, bq, q_ws, M, D_MODEL, D_MODEL);
        gemm_bias_kernel<1><<<ggrid, 256, 0, stream>>>(key_,  Wk, bk, k_ws, M, D_MODEL, D_MODEL);
        gemm_bias_kernel<1><<<ggrid, 256, 0, stream>>>(value, Wv, bv, v_ws, M, D_MODEL, D_MODEL);
        dim3 agrid(SEQ / 256, NUM_HEADS, BATCH);
        attn_fp32_kernel<<<agrid, 256, 0, stream>>>(q_ws, k_ws, v_ws, mask, c_ws);
        gemm_bias_kernel<0><<<ggrid, 256, 0, stream>>>(c_ws, Wo, bo, out, M, D_MODEL, D_MODEL);
    }
}